// Round 1
// 228.514 us; speedup vs baseline: 1.0282x; 1.0282x over previous
//
#include <hip/hip_runtime.h>

#define CHAR_EMB 30
#define NFILT    30
#define WLEN     40
#define TOUT     38      // WLEN - K + 1
#define OUTC     900     // CHAR_EMB * NFILT
#define WORD_EMB 100
#define RP2      42      // LDS row stride in f32x2 (42*8 = 336 B, 16B aligned)

typedef float f32x2 __attribute__((ext_vector_type(2)));
typedef float f32x4 __attribute__((ext_vector_type(4)));

// Guaranteed packed fp32 math — do not rely on SLP forming <2 x float>.
__device__ __forceinline__ f32x2 pk_fma(f32x2 a, f32x2 b, f32x2 c) {
    f32x2 d;
    asm("v_pk_fma_f32 %0, %1, %2, %3" : "=v"(d) : "v"(a), "v"(b), "v"(c));
    return d;
}
__device__ __forceinline__ f32x2 pk_mul(f32x2 a, f32x2 b) {
    f32x2 d;
    asm("v_pk_mul_f32 %0, %1, %2" : "=v"(d) : "v"(a), "v"(b));
    return d;
}
__device__ __forceinline__ float max3f(float a, float b, float c) {
    float d;
    asm("v_max3_f32 %0, %1, %2, %3" : "=v"(d) : "v"(a), "v"(b), "v"(c));
    return d;
}

// One block = TWO consecutive words packed in the two lanes of f32x2.
// Threads 0..239: group g = tid/8 (input channel), filter phase j = tid%8,
// filters f = j + {0,8,16,24} (< 30). Threads 240..255: glove copy
// (overlaps the conv phase instead of serializing with it).
__global__ __launch_bounds__(256, 4) void encoder_kernel(
    const int*   __restrict__ char_ids,   // [BS, 40]
    const int*   __restrict__ word_ids,   // [BS]
    const float* __restrict__ char_emb,   // [102, 30]
    const float* __restrict__ conv_w,     // [900, 1, 3]
    const float* __restrict__ conv_b,     // [900]
    const float* __restrict__ glove,      // [400002, 100]
    float*       __restrict__ out,        // [BS, 1000]
    int BS)
{
    const int nA   = 2 * blockIdx.x;
    const int nB   = nA + 1;
    const bool hasB = (nB < BS);
    const int tid  = threadIdx.x;

    __shared__ int cid[2 * WLEN];
    __shared__ __align__(16) f32x2 xs[CHAR_EMB * RP2];  // xs[c*RP2+t] = {xA[c][t], xB[c][t]}

    float* orowA = out + (long)nA * (OUTC + WORD_EMB);
    float* orowB = out + (long)nB * (OUTC + WORD_EMB);

    // stage char ids: rows nA,nB are contiguous (80 consecutive ints)
    if (tid < 2 * WLEN) {
        cid[tid] = (tid < WLEN || hasB) ? char_ids[nA * WLEN + tid] : 0;
    }
    __syncthreads();

    // gather char embeddings for both words: 1200 (t,c) pairs -> f32x2 LDS
    for (int i = tid; i < WLEN * CHAR_EMB; i += 256) {
        const int t = i / CHAR_EMB;
        const int c = i - t * CHAR_EMB;
        const float a = char_emb[cid[t] * CHAR_EMB + c];
        const float b = char_emb[cid[WLEN + t] * CHAR_EMB + c];
        f32x2 v; v.x = a; v.y = b;
        xs[c * RP2 + t] = v;
    }
    __syncthreads();

    if (tid < 240) {
        const int g = tid >> 3;        // group / input channel 0..29
        const int j = tid & 7;         // filter phase 0..7

        // weights + bias for the 4 filter slots (zeros for the invalid slot)
        f32x2 W0[4], W1[4], W2[4];
        float bias[4];
        int   oc[4];
        #pragma unroll
        for (int u = 0; u < 4; ++u) {
            const int f = j + 8 * u;
            float w0 = 0.f, w1 = 0.f, w2 = 0.f, bb = 0.f;
            if (f < NFILT) {
                const int o = g * NFILT + f;
                oc[u] = o;
                w0 = conv_w[o * 3 + 0];
                w1 = conv_w[o * 3 + 1];
                w2 = conv_w[o * 3 + 2];
                bb = conv_b[o];
            } else {
                oc[u] = -1;
            }
            W0[u].x = w0; W0[u].y = w0;
            W1[u].x = w1; W1[u].y = w1;
            W2[u].x = w2; W2[u].y = w2;
            bias[u] = bb;
        }

        f32x2 m[4];
        #pragma unroll
        for (int u = 0; u < 4; ++u) { m[u].x = -3.4e38f; m[u].y = -3.4e38f; }

        const f32x4* rp = reinterpret_cast<const f32x4*>(&xs[g * RP2]);

        // ---- half A: output pairs i=0..9 (t=0..19), needs x[0..21] ----
        {
            f32x4 q[11];
            #pragma unroll
            for (int k = 0; k < 11; ++k) q[k] = rp[k];
            #define XA(t) (((t) & 1) ? q[(t) >> 1].zw : q[(t) >> 1].xy)
            #pragma unroll
            for (int i = 0; i < 10; ++i) {
                const f32x2 x0 = XA(2 * i + 0);
                const f32x2 x1 = XA(2 * i + 1);
                const f32x2 x2 = XA(2 * i + 2);
                const f32x2 x3 = XA(2 * i + 3);
                #pragma unroll
                for (int u = 0; u < 4; ++u) {
                    const f32x2 v0 = pk_fma(W0[u], x0, pk_fma(W1[u], x1, pk_mul(W2[u], x2)));
                    const f32x2 v1 = pk_fma(W0[u], x1, pk_fma(W1[u], x2, pk_mul(W2[u], x3)));
                    m[u].x = max3f(m[u].x, v0.x, v1.x);
                    m[u].y = max3f(m[u].y, v0.y, v1.y);
                }
            }
            #undef XA
        }

        // ---- half B: output pairs i=10..18 (t=20..36), needs x[20..39] ----
        {
            f32x4 q[10];
            #pragma unroll
            for (int k = 0; k < 10; ++k) q[k] = rp[10 + k];
            // x[20+s] : s in [0,19]
            #define XB(s) (((s) & 1) ? q[(s) >> 1].zw : q[(s) >> 1].xy)
            #pragma unroll
            for (int i = 0; i < 9; ++i) {
                const int s = 2 * i;     // s = t - 20, t = 20 + 2i
                const f32x2 x0 = XB(s + 0);
                const f32x2 x1 = XB(s + 1);
                const f32x2 x2 = XB(s + 2);
                const f32x2 x3 = XB(s + 3);
                #pragma unroll
                for (int u = 0; u < 4; ++u) {
                    const f32x2 v0 = pk_fma(W0[u], x0, pk_fma(W1[u], x1, pk_mul(W2[u], x2)));
                    const f32x2 v1 = pk_fma(W0[u], x1, pk_fma(W1[u], x2, pk_mul(W2[u], x3)));
                    m[u].x = max3f(m[u].x, v0.x, v1.x);
                    m[u].y = max3f(m[u].y, v0.y, v1.y);
                }
            }
            #undef XB
        }

        #pragma unroll
        for (int u = 0; u < 4; ++u) {
            if (oc[u] >= 0) {
                orowA[oc[u]] = m[u].x + bias[u];
                if (hasB) orowB[oc[u]] = m[u].y + bias[u];
            }
        }
    } else {
        // threads 240..255: glove row copies, overlapped with conv
        const int k = tid - 240;
        {
            const f32x4* gp = reinterpret_cast<const f32x4*>(glove + (long)word_ids[nA] * WORD_EMB);
            f32x4* op = reinterpret_cast<f32x4*>(orowA + OUTC);
            #pragma unroll
            for (int q = 0; q < 2; ++q) {
                const int idx = k + 16 * q;
                if (idx < WORD_EMB / 4) op[idx] = gp[idx];
            }
        }
        if (hasB) {
            const f32x4* gp = reinterpret_cast<const f32x4*>(glove + (long)word_ids[nB] * WORD_EMB);
            f32x4* op = reinterpret_cast<f32x4*>(orowB + OUTC);
            #pragma unroll
            for (int q = 0; q < 2; ++q) {
                const int idx = k + 16 * q;
                if (idx < WORD_EMB / 4) op[idx] = gp[idx];
            }
        }
    }
}

extern "C" void kernel_launch(void* const* d_in, const int* in_sizes, int n_in,
                              void* d_out, int out_size, void* d_ws, size_t ws_size,
                              hipStream_t stream) {
    const int*   char_ids = (const int*)  d_in[0];
    const int*   word_ids = (const int*)  d_in[1];
    const float* char_emb = (const float*)d_in[2];
    const float* conv_w   = (const float*)d_in[3];
    const float* conv_b   = (const float*)d_in[4];
    const float* glove    = (const float*)d_in[5];
    float*       out      = (float*)      d_out;

    const int BS = in_sizes[1];          // 8192 words
    const int nblk = (BS + 1) / 2;

    encoder_kernel<<<nblk, 256, 0, stream>>>(
        char_ids, word_ids, char_emb, conv_w, conv_b, glove, out, BS);
}

// Round 2
// 228.251 us; speedup vs baseline: 1.0294x; 1.0012x over previous
//
#include <hip/hip_runtime.h>

#define CHAR_EMB 30
#define NFILT    30
#define WLEN     40
#define TOUT     38      // WLEN - K + 1
#define OUTC     900     // CHAR_EMB * NFILT
#define WORD_EMB 100
#define RP2      42      // LDS row stride in f32x2 (42*8 = 336 B, 16B aligned)

typedef float f32x2 __attribute__((ext_vector_type(2)));
typedef float f32x4 __attribute__((ext_vector_type(4)));

// Guaranteed packed fp32 math — do not rely on SLP forming <2 x float>.
__device__ __forceinline__ f32x2 pk_fma(f32x2 a, f32x2 b, f32x2 c) {
    f32x2 d;
    asm("v_pk_fma_f32 %0, %1, %2, %3" : "=v"(d) : "v"(a), "v"(b), "v"(c));
    return d;
}
__device__ __forceinline__ f32x2 pk_mul(f32x2 a, f32x2 b) {
    f32x2 d;
    asm("v_pk_mul_f32 %0, %1, %2" : "=v"(d) : "v"(a), "v"(b));
    return d;
}
__device__ __forceinline__ float max3f(float a, float b, float c) {
    float d;
    asm("v_max3_f32 %0, %1, %2, %3" : "=v"(d) : "v"(a), "v"(b), "v"(c));
    return d;
}

// One block = TWO consecutive words packed in the two lanes of f32x2.
// Threads 0..239: group g = tid/8 (input channel), filter phase j = tid%8,
// filters f = j + {0,8,16,24} (< 30). Threads 240..255: glove copy.
// Conv streams the 40-position LDS row through a 2-register rolling window
// (cur/nxt) instead of staging 21 f32x4 in registers: live VGPRs ~52 ->
// __launch_bounds__(256,8) caps at 64 VGPR = 8 waves/SIMD (2x occupancy).
__global__ __launch_bounds__(256, 8) void encoder_kernel(
    const int*   __restrict__ char_ids,   // [BS, 40]
    const int*   __restrict__ word_ids,   // [BS]
    const float* __restrict__ char_emb,   // [102, 30]
    const float* __restrict__ conv_w,     // [900, 1, 3]
    const float* __restrict__ conv_b,     // [900]
    const float* __restrict__ glove,      // [400002, 100]
    float*       __restrict__ out,        // [BS, 1000]
    int BS)
{
    const int nA   = 2 * blockIdx.x;
    const int nB   = nA + 1;
    const bool hasB = (nB < BS);
    const int tid  = threadIdx.x;

    __shared__ int cid[2 * WLEN];
    __shared__ __align__(16) f32x2 xs[CHAR_EMB * RP2];  // xs[c*RP2+t] = {xA[c][t], xB[c][t]}

    float* orowA = out + (long)nA * (OUTC + WORD_EMB);
    float* orowB = out + (long)nB * (OUTC + WORD_EMB);

    // stage char ids: rows nA,nB are contiguous (80 consecutive ints)
    if (tid < 2 * WLEN) {
        cid[tid] = (tid < WLEN || hasB) ? char_ids[nA * WLEN + tid] : 0;
    }
    __syncthreads();

    // gather char embeddings, float2 over channel pairs:
    // 600 items = 40 positions x 15 channel-pairs; each item loads f32x2
    // from word A's row and word B's row, writes two LDS f32x2 entries.
    for (int i = tid; i < WLEN * (CHAR_EMB / 2); i += 256) {
        const int t  = i / (CHAR_EMB / 2);
        const int cp = i - t * (CHAR_EMB / 2);
        const int c  = 2 * cp;
        const f32x2 a = *reinterpret_cast<const f32x2*>(char_emb + cid[t] * CHAR_EMB + c);
        const f32x2 b = *reinterpret_cast<const f32x2*>(char_emb + cid[WLEN + t] * CHAR_EMB + c);
        f32x2 v0; v0.x = a.x; v0.y = b.x;
        f32x2 v1; v1.x = a.y; v1.y = b.y;
        xs[(c    ) * RP2 + t] = v0;
        xs[(c + 1) * RP2 + t] = v1;
    }
    __syncthreads();

    if (tid < 240) {
        const int g = tid >> 3;        // group / input channel 0..29
        const int j = tid & 7;         // filter phase 0..7

        // weights + bias for the 4 filter slots (zeros for invalid slots)
        f32x2 W0[4], W1[4], W2[4];
        float bias[4];
        #pragma unroll
        for (int u = 0; u < 4; ++u) {
            const int f = j + 8 * u;
            float w0 = 0.f, w1 = 0.f, w2 = 0.f, bb = 0.f;
            if (f < NFILT) {
                const int o = g * NFILT + f;
                w0 = conv_w[o * 3 + 0];
                w1 = conv_w[o * 3 + 1];
                w2 = conv_w[o * 3 + 2];
                bb = conv_b[o];
            }
            W0[u].x = w0; W0[u].y = w0;
            W1[u].x = w1; W1[u].y = w1;
            W2[u].x = w2; W2[u].y = w2;
            bias[u] = bb;
        }

        f32x2 m[4];
        #pragma unroll
        for (int u = 0; u < 4; ++u) { m[u].x = -3.4e38f; m[u].y = -3.4e38f; }

        // rolling-window stream over the row: rp[k] = {x[2k], x[2k+1]} (A,B packed)
        const f32x4* rp = reinterpret_cast<const f32x4*>(&xs[g * RP2]);
        f32x4 cur = rp[0];
        #pragma unroll 2
        for (int k = 0; k < 19; ++k) {
            const f32x4 nxt = rp[k + 1];
            const f32x2 x0 = cur.xy;   // pos 2k
            const f32x2 x1 = cur.zw;   // pos 2k+1
            const f32x2 x2 = nxt.xy;   // pos 2k+2
            const f32x2 x3 = nxt.zw;   // pos 2k+3
            #pragma unroll
            for (int u = 0; u < 4; ++u) {
                const f32x2 v0 = pk_fma(W0[u], x0, pk_fma(W1[u], x1, pk_mul(W2[u], x2)));
                const f32x2 v1 = pk_fma(W0[u], x1, pk_fma(W1[u], x2, pk_mul(W2[u], x3)));
                m[u].x = max3f(m[u].x, v0.x, v1.x);
                m[u].y = max3f(m[u].y, v0.y, v1.y);
            }
            cur = nxt;
        }

        #pragma unroll
        for (int u = 0; u < 4; ++u) {
            const int f = j + 8 * u;
            if (f < NFILT) {
                const int o = g * NFILT + f;
                const float bb = bias[u];
                orowA[o] = m[u].x + bb;
                if (hasB) orowB[o] = m[u].y + bb;
            }
        }
    } else {
        // threads 240..255: glove row copies, overlapped with conv
        const int k = tid - 240;
        {
            const f32x4* gp = reinterpret_cast<const f32x4*>(glove + (long)word_ids[nA] * WORD_EMB);
            f32x4* op = reinterpret_cast<f32x4*>(orowA + OUTC);
            #pragma unroll
            for (int q = 0; q < 2; ++q) {
                const int idx = k + 16 * q;
                if (idx < WORD_EMB / 4) op[idx] = gp[idx];
            }
        }
        if (hasB) {
            const f32x4* gp = reinterpret_cast<const f32x4*>(glove + (long)word_ids[nB] * WORD_EMB);
            f32x4* op = reinterpret_cast<f32x4*>(orowB + OUTC);
            #pragma unroll
            for (int q = 0; q < 2; ++q) {
                const int idx = k + 16 * q;
                if (idx < WORD_EMB / 4) op[idx] = gp[idx];
            }
        }
    }
}

extern "C" void kernel_launch(void* const* d_in, const int* in_sizes, int n_in,
                              void* d_out, int out_size, void* d_ws, size_t ws_size,
                              hipStream_t stream) {
    const int*   char_ids = (const int*)  d_in[0];
    const int*   word_ids = (const int*)  d_in[1];
    const float* char_emb = (const float*)d_in[2];
    const float* conv_w   = (const float*)d_in[3];
    const float* conv_b   = (const float*)d_in[4];
    const float* glove    = (const float*)d_in[5];
    float*       out      = (float*)      d_out;

    const int BS = in_sizes[1];          // 8192 words
    const int nblk = (BS + 1) / 2;

    encoder_kernel<<<nblk, 256, 0, stream>>>(
        char_ids, word_ids, char_emb, conv_w, conv_b, glove, out, BS);
}